// Round 1
// baseline (278.348 us; speedup 1.0000x reference)
//
#include <hip/hip_runtime.h>

// Problem: inputs [B=64, H=56, W=56, C=256] fp32, NHWC (C innermost).
// Output: max over (H,W) -> [B, C] = 16384 floats.
// Memory-bound: 205.5 MB read. Two-pass partial-max reduction.

#define BATCH   64
#define HW      3136          // 56*56
#define CH      256
#define CHUNKS  16
#define POS_PER_CHUNK (HW / CHUNKS)   // 196

__device__ __forceinline__ float4 f4max(float4 a, float4 b) {
    float4 r;
    r.x = fmaxf(a.x, b.x);
    r.y = fmaxf(a.y, b.y);
    r.z = fmaxf(a.z, b.z);
    r.w = fmaxf(a.w, b.w);
    return r;
}

// Kernel 1: per (batch b, spatial chunk), reduce 196 positions -> one [CH]
// partial row in ws. Block = 256 threads = 4 wave-groups of 64; lane c4 owns
// channels [4*c4, 4*c4+4) via float4 (16 B/lane coalesced). Group g takes
// positions base+4*it+g.
__global__ __launch_bounds__(256)
void gmax_partial(const float* __restrict__ in, float* __restrict__ ws) {
    const int b     = blockIdx.x;
    const int chunk = blockIdx.y;
    const int tid   = threadIdx.x;
    const int g     = tid >> 6;    // 0..3
    const int c4    = tid & 63;    // float4 index over channels

    const float4* inp = reinterpret_cast<const float4*>(
        in + (size_t)b * HW * CH);

    float4 m = make_float4(-INFINITY, -INFINITY, -INFINITY, -INFINITY);
    const int base = chunk * POS_PER_CHUNK;

    #pragma unroll 7
    for (int it = 0; it < POS_PER_CHUNK / 4; ++it) {   // 49 iterations
        const int pos = base + it * 4 + g;
        float4 v = inp[(size_t)pos * (CH / 4) + c4];
        m = f4max(m, v);
    }

    __shared__ float4 red[4][64];
    red[g][c4] = m;
    __syncthreads();

    if (g == 0) {
        float4 r = f4max(f4max(red[0][c4], red[1][c4]),
                         f4max(red[2][c4], red[3][c4]));
        float4* wsp = reinterpret_cast<float4*>(ws) +
                      ((size_t)b * CHUNKS + chunk) * (CH / 4);
        wsp[c4] = r;
    }
}

// Kernel 2: out[b][c] = max over CHUNKS partials.
__global__ __launch_bounds__(256)
void gmax_final(const float* __restrict__ ws, float* __restrict__ out) {
    const int b = blockIdx.x;
    const int c = threadIdx.x;
    float m = -INFINITY;
    #pragma unroll
    for (int k = 0; k < CHUNKS; ++k)
        m = fmaxf(m, ws[((size_t)b * CHUNKS + k) * CH + c]);
    out[(size_t)b * CH + c] = m;
}

extern "C" void kernel_launch(void* const* d_in, const int* in_sizes, int n_in,
                              void* d_out, int out_size, void* d_ws, size_t ws_size,
                              hipStream_t stream) {
    const float* in = (const float*)d_in[0];
    float* out = (float*)d_out;
    float* ws  = (float*)d_ws;   // needs BATCH*CHUNKS*CH*4 = 1 MB... (64*16*256*4 = 1,048,576 B? no: 64*16*256 = 262144 floats = 1 MB)

    dim3 grid1(BATCH, CHUNKS);
    gmax_partial<<<grid1, 256, 0, stream>>>(in, ws);
    gmax_final<<<BATCH, 256, 0, stream>>>(ws, out);
}

// Round 2
// 276.574 us; speedup vs baseline: 1.0064x; 1.0064x over previous
//
#include <hip/hip_runtime.h>

// [B=64, H=56, W=56, C=256] fp32 NHWC -> max over (H,W) -> [B, C].
// Memory-bound: 205.5 MB read, 64 KB write. Floor ~33 us at 6.3 TB/s.
//
// Pass 1: grid (64 batches x 49 chunks) = 3136 blocks (12/CU), 256 thr = 4 waves.
//         Chunk = 64 consecutive spatial positions (64 KB contiguous).
//         Wave g handles positions g, g+4, ..., g+60: 16 fully-unrolled float4
//         loads (16 B/lane, 1 KB/wave/position, all 16 in flight), 2 accumulators.
// Pass 2: 64 blocks x 256 thr, max over 49 partials -> d_out. (3.2 MB, ~3 us)

#define BATCH   64
#define HW      3136
#define CH      256
#define CHUNKS  49
#define POS     64            // positions per chunk (HW / CHUNKS)

__device__ __forceinline__ float4 f4max(float4 a, float4 b) {
    float4 r;
    r.x = fmaxf(a.x, b.x);
    r.y = fmaxf(a.y, b.y);
    r.z = fmaxf(a.z, b.z);
    r.w = fmaxf(a.w, b.w);
    return r;
}

__global__ __launch_bounds__(256)
void gmax_partial(const float* __restrict__ in, float* __restrict__ ws) {
    const int b     = blockIdx.x;
    const int chunk = blockIdx.y;
    const int g     = threadIdx.x >> 6;   // wave id 0..3
    const int c4    = threadIdx.x & 63;   // float4 channel index

    // Base: batch b, position chunk*64, this lane's 16B channel slot.
    const float4* __restrict__ p = reinterpret_cast<const float4*>(in)
        + ((size_t)b * HW + (size_t)chunk * POS) * (CH / 4) + c4;

    float4 m0 = make_float4(-INFINITY, -INFINITY, -INFINITY, -INFINITY);
    float4 m1 = m0;

    // Wave g: positions g, g+4, ..., g+60 (16 of them), fully unrolled so all
    // 16 independent 1KB-per-wave loads are in flight; 2 accumulators break
    // the fmax dependence chain.
    #pragma unroll
    for (int it = 0; it < 16; it += 2) {
        float4 v0 = p[(size_t)((it + 0) * 4 + g) * (CH / 4)];
        float4 v1 = p[(size_t)((it + 1) * 4 + g) * (CH / 4)];
        m0 = f4max(m0, v0);
        m1 = f4max(m1, v1);
    }
    m0 = f4max(m0, m1);

    __shared__ float4 red[4][64];
    red[g][c4] = m0;
    __syncthreads();

    if (g == 0) {
        float4 r = f4max(f4max(red[0][c4], red[1][c4]),
                         f4max(red[2][c4], red[3][c4]));
        reinterpret_cast<float4*>(ws)
            [((size_t)b * CHUNKS + chunk) * (CH / 4) + c4] = r;
    }
}

__global__ __launch_bounds__(256)
void gmax_final(const float* __restrict__ ws, float* __restrict__ out) {
    const int b = blockIdx.x;
    const int c = threadIdx.x;
    float m = -INFINITY;
    #pragma unroll
    for (int k = 0; k < CHUNKS; ++k)
        m = fmaxf(m, ws[((size_t)b * CHUNKS + k) * CH + c]);
    out[(size_t)b * CH + c] = m;
}

extern "C" void kernel_launch(void* const* d_in, const int* in_sizes, int n_in,
                              void* d_out, int out_size, void* d_ws, size_t ws_size,
                              hipStream_t stream) {
    const float* in = (const float*)d_in[0];
    float* out = (float*)d_out;
    float* ws  = (float*)d_ws;   // 64*49*256*4 B = 3.2 MB used

    dim3 grid1(BATCH, CHUNKS);
    gmax_partial<<<grid1, 256, 0, stream>>>(in, ws);
    gmax_final<<<BATCH, 256, 0, stream>>>(ws, out);
}